// Round 7
// baseline (103.027 us; speedup 1.0000x reference)
//
#include <hip/hip_runtime.h>
#include <math.h>

#define MITEMS 2   // priors per thread in match
#define TILE 512   // 256 * MITEMS
#define LB 32      // blocks per batch for loss/hist/sum kernels

// ---------------------------------------------------------------------------
// ws layout:
//   header (memset 0 each call): pconf[B], ploc[B], phard[B], n_pos[B], counter,
//                                M[B][64] (iou bits), win[B][64] (0xFFFFFFFF-p)
//   hist0[B][4096], hist1[B][4096]   <- zeroed by recover kernel
//   float conf_neg[B*P]
//   u8    best_u8[B*P]   : bit7 = (best iou >= 0.5), bits0-6 = best obj
//   u32   part_max[B*nblk*NOBJT]     : per-block per-object max iou bits
// ---------------------------------------------------------------------------

// Bit-deterministic helpers shared by match and recover (no FMA contraction).
__device__ __forceinline__ void prep_prior(const float* __restrict__ pr,
                                           float& lo0, float& lo1, float& lo2,
                                           float& hi0, float& hi1, float& hi2,
                                           float& vb) {
  const float2 q0 = *(const float2*)(pr);
  const float2 q1 = *(const float2*)(pr + 2);
  const float2 q2 = *(const float2*)(pr + 4);
  const float h0 = __fmul_rn(q1.y, 0.5f);
  const float h1 = __fmul_rn(q2.x, 0.5f);
  const float h2 = __fmul_rn(q2.y, 0.5f);
  lo0 = __fadd_rn(q0.x, -h0); hi0 = __fadd_rn(q0.x, h0);
  lo1 = __fadd_rn(q0.y, -h1); hi1 = __fadd_rn(q0.y, h1);
  lo2 = __fadd_rn(q1.x, -h2); hi2 = __fadd_rn(q1.x, h2);
  vb = __fmul_rn(__fmul_rn(q1.y, q2.x), q2.y);
}

__device__ __forceinline__ void make_box(const float* __restrict__ bx,
                                         float4& c0, float4& c1) {
  const float l0 = bx[0], l1 = bx[1], l2 = bx[2];
  const float h0 = bx[3], h1 = bx[4], h2 = bx[5];
  c0 = make_float4(l0, l1, l2, h0);
  const float vol = __fmul_rn(
      __fmul_rn(__fadd_rn(h0, -l0), __fadd_rn(h1, -l1)), __fadd_rn(h2, -l2));
  c1 = make_float4(h1, h2, vol, 0.f);
}

__device__ __forceinline__ float iou6(float lo0, float lo1, float lo2, float hi0,
                                      float hi1, float hi2, float vb,
                                      const float4& c0, const float4& c1) {
  const float d0 = __fadd_rn(fminf(c0.w, hi0), -fmaxf(c0.x, lo0));
  const float d1 = __fadd_rn(fminf(c1.x, hi1), -fmaxf(c0.y, lo1));
  const float d2 = __fadd_rn(fminf(c1.y, hi2), -fmaxf(c0.z, lo2));
  const float e0 = fmaxf(d0, 0.f), e1 = fmaxf(d1, 0.f), e2 = fmaxf(d2, 0.f);
  const float inter = __fmul_rn(__fmul_rn(e0, e1), e2);
  const float un = __fadd_rn(__fadd_rn(c1.z, vb), -inter);
  return __fmul_rn(inter, __builtin_amdgcn_rcpf(un));
}

// Phase 1: per-prior best object (exact) + per-object per-block MAX IOU VALUE.
template <int NOBJ, bool FULL>
__global__ __launch_bounds__(256) void mbl_match(
    const float* __restrict__ boxes, const float* __restrict__ priors,
    unsigned* __restrict__ part_max, unsigned* __restrict__ M,
    unsigned char* __restrict__ best_u8, int P, int n_obj) {
  const int b = blockIdx.y;
  const int tid = threadIdx.x;
  __shared__ float4 s_box[NOBJ][2];
  __shared__ unsigned s_tr[16][264];
  for (int i = tid; i < NOBJ; i += 256) {
    if (i < n_obj) {
      make_box(boxes + ((size_t)b * n_obj + i) * 6, s_box[i][0], s_box[i][1]);
    } else {  // dummy object: iou 0 vs everything
      s_box[i][0] = make_float4(3e18f, 3e18f, 3e18f, 1e18f);
      s_box[i][1] = make_float4(1e18f, 1e18f, 1.0f, 0.f);
    }
  }
  __syncthreads();

  float lo0[MITEMS], lo1[MITEMS], lo2[MITEMS], hi0[MITEMS], hi1[MITEMS],
      hi2[MITEMS], vb[MITEMS];
  const int base = blockIdx.x * TILE;
#pragma unroll
  for (int k = 0; k < MITEMS; ++k) {
    const int p = base + k * 256 + tid;
    if (FULL || p < P) {
      prep_prior(priors + (size_t)p * 6, lo0[k], lo1[k], lo2[k], hi0[k], hi1[k],
                 hi2[k], vb[k]);
    } else {  // dummy prior: iou 0 vs everything
      lo0[k] = lo1[k] = lo2[k] = 3e18f;
      hi0[k] = hi1[k] = hi2[k] = 3e18f;
      vb[k] = 0.f;
    }
  }

  float piou[NOBJ];
#pragma unroll
  for (int o = 0; o < NOBJ; ++o) piou[o] = 0.f;
  float bv[MITEMS];
  int bo[MITEMS];
#pragma unroll
  for (int k = 0; k < MITEMS; ++k) { bv[k] = -1.0f; bo[k] = 0; }

#pragma unroll
  for (int o = 0; o < NOBJ; ++o) {
    const float4 c0 = s_box[o][0];
    const float4 c1 = s_box[o][1];
#pragma unroll
    for (int k = 0; k < MITEMS; ++k) {
      const float iou = iou6(lo0[k], lo1[k], lo2[k], hi0[k], hi1[k], hi2[k],
                             vb[k], c0, c1);
      const bool g = iou > bv[k];  // first-occurrence argmax over objects
      bv[k] = g ? iou : bv[k];
      bo[k] = g ? o : bo[k];
      piou[o] = fmaxf(piou[o], iou);  // value only — index recovered later
    }
  }

#pragma unroll
  for (int k = 0; k < MITEMS; ++k) {
    const int p = base + k * 256 + tid;
    if (FULL || p < P)
      best_u8[(size_t)b * P + p] =
          (unsigned char)((unsigned)bo[k] | (bv[k] >= 0.5f ? 0x80u : 0u));
  }

  // Epilogue: block-reduce piou via LDS transpose (16 objects per pass).
  for (int o0 = 0; o0 < NOBJ; o0 += 16) {
    if (o0) __syncthreads();
#pragma unroll
    for (int o = 0; o < NOBJ; ++o)
      if (o >= o0 && o < o0 + 16) s_tr[o - o0][tid] = __float_as_uint(piou[o]);
    __syncthreads();
    const int obj = tid >> 4, j = tid & 15;
    unsigned m = 0u;
#pragma unroll
    for (int i = 0; i < 16; ++i) m = max(m, s_tr[obj][j + 16 * i]);
#pragma unroll
    for (int off = 1; off < 16; off <<= 1) m = max(m, __shfl_xor(m, off, 64));
    if (j == 0) {
      const int o = o0 + obj;
      if (o < n_obj) {
        part_max[((size_t)b * gridDim.x + blockIdx.x) * NOBJ + o] = m;
        atomicMax(&M[(size_t)b * 64 + o], m);
      }
    }
  }
}

// Phase 2: winner blocks rescan (bit-identical recompute) -> exact argmax.
// Also zeroes the histogram region.
template <bool FULL>
__global__ __launch_bounds__(256) void mbl_recover(
    const float* __restrict__ boxes, const float* __restrict__ priors,
    const unsigned* __restrict__ part_max, const unsigned* __restrict__ M,
    unsigned* __restrict__ win, unsigned long long* __restrict__ zero_buf,
    int zero_words, int P, int n_obj, int nobjT) {
  const int b = blockIdx.y;
  const int blk = blockIdx.x;
  const int tid = threadIdx.x;
  {  // zero duty for hist0/hist1
    const int gid = b * gridDim.x + blk;
    const int total = (int)(gridDim.x * gridDim.y) * 256;
    for (int i = gid * 256 + tid; i < zero_words; i += total) zero_buf[i] = 0ULL;
  }
  __shared__ unsigned s_mu[64];
  __shared__ int s_hit[64];
  if (tid < 64) {
    unsigned mu = 0u;
    int hit = 0;
    if (tid < n_obj && tid < nobjT) {
      mu = M[(size_t)b * 64 + tid];
      const unsigned pm = part_max[((size_t)b * gridDim.x + blk) * nobjT + tid];
      hit = (pm == mu);
    }
    s_mu[tid] = mu;
    s_hit[tid] = hit;
  }
  __syncthreads();

  const int base = blk * TILE;
  for (int o = 0; o < n_obj; ++o) {
    if (!s_hit[o]) continue;
    float4 c0, c1;
    make_box(boxes + ((size_t)b * n_obj + o) * 6, c0, c1);
    const unsigned target = s_mu[o];
#pragma unroll
    for (int k = 0; k < MITEMS; ++k) {
      const int p = base + k * 256 + tid;
      if (FULL || p < P) {
        float lo0, lo1, lo2, hi0, hi1, hi2, vb;
        prep_prior(priors + (size_t)p * 6, lo0, lo1, lo2, hi0, hi1, hi2, vb);
        const float iou = iou6(lo0, lo1, lo2, hi0, hi1, hi2, vb, c0, c1);
        if (__float_as_uint(iou) == target)
          atomicMax(&win[(size_t)b * 64 + o], 0xFFFFFFFFu - (unsigned)p);
      }
    }
  }
}

// Labels (incl. inline forced-match override), CE, loc L1, conf_neg + hist0.
template <int CC>
__global__ __launch_bounds__(256) void mbl_loss(
    const float* __restrict__ locs, const float* __restrict__ scores,
    const float* __restrict__ boxes, const int* __restrict__ labels,
    const float* __restrict__ priors, const unsigned* __restrict__ win,
    const unsigned char* __restrict__ best_u8, float* __restrict__ conf_neg,
    unsigned* __restrict__ hist0, int* __restrict__ n_pos,
    double* __restrict__ pconf, double* __restrict__ ploc, int P, int n_obj,
    int C) {
  const int b = blockIdx.y;
  const int tid = threadIdx.x;
  __shared__ float s_box[64][6];
  __shared__ int s_lab[64];
  __shared__ unsigned s_fo[64];
  __shared__ unsigned s_hist[4096];
  for (int i = tid; i < 4096; i += 256) s_hist[i] = 0u;
  for (int i = tid; i < n_obj * 6; i += 256)
    s_box[i / 6][i % 6] = boxes[(size_t)b * n_obj * 6 + i];
  for (int i = tid; i < n_obj; i += 256) {
    s_lab[i] = labels[(size_t)b * n_obj + i];
    s_fo[i] = 0xFFFFFFFFu - win[(size_t)b * 64 + i];  // forced prior index
  }
  __syncthreads();

  unsigned fo_r[16];
  const bool small_obj = (n_obj <= 16);
  if (small_obj) {
#pragma unroll
    for (int o = 0; o < 16; ++o) fo_r[o] = (o < n_obj) ? s_fo[o] : 0xFFFFFFFEu;
  }

  const int chunk = (P + gridDim.x - 1) / gridDim.x;
  const int start = blockIdx.x * chunk;
  const int end = min(start + chunk, P);
  int np_l = 0;
  double cf_l = 0.0, lc_l = 0.0;
  for (int p = start + tid; p < end; p += 256) {
    const unsigned char bp = best_u8[(size_t)b * P + p];
    int obj = bp & 0x7F;
    int posf = bp >> 7;
    if (small_obj) {
#pragma unroll
      for (int o = 0; o < 16; ++o)
        if (fo_r[o] == (unsigned)p) { obj = o; posf = 1; }  // last wins
    } else {
      for (int o = 0; o < n_obj; ++o)
        if (s_fo[o] == (unsigned)p) { obj = o; posf = 1; }
    }
    const int lab = posf ? s_lab[obj] : 0;

    float conf;
    if (CC == 2) {
      const float2 sc = *(const float2*)(scores + ((size_t)b * P + p) * 2);
      const float m = fmaxf(sc.x, sc.y);
      conf = (lab < 0) ? 0.f
                       : (m + __logf(__expf(sc.x - m) + __expf(sc.y - m)) -
                          ((lab == 0) ? sc.x : sc.y));
    } else {
      const float* sp = scores + ((size_t)b * P + p) * C;
      float m = sp[0];
      for (int c = 1; c < C; ++c) m = fmaxf(m, sp[c]);
      float se = 0.f;
      for (int c = 0; c < C; ++c) se += __expf(sp[c] - m);
      conf = (lab < 0) ? 0.f : (m + __logf(se) - sp[lab]);
    }

    float cn = conf;
    if (lab > 0) {
      np_l++;
      cf_l += (double)conf;
      const float* pr = priors + (size_t)p * 6;
      const float* pl = locs + ((size_t)b * P + p) * 6;
      float ls = 0.f;
      for (int i = 0; i < 3; ++i) {
        const float c0 = (s_box[obj][i] + s_box[obj][i + 3]) * 0.5f;
        const float szb = s_box[obj][i + 3] - s_box[obj][i];
        const float g = (c0 - pr[i]) / (pr[i + 3] / 10.0f);
        const float g2 = logf(szb / pr[i + 3]) * 5.0f;
        ls += fabsf(pl[i] - g) + fabsf(pl[i + 3] - g2);
      }
      lc_l += (double)ls;
      cn = 0.f;
    }
    conf_neg[(size_t)b * P + p] = cn;
    atomicAdd(&s_hist[__float_as_uint(cn) >> 20], 1u);
  }

  __shared__ int r_np[256];
  __shared__ double r_c[256];
  __shared__ double r_l[256];
  r_np[tid] = np_l;
  r_c[tid] = cf_l;
  r_l[tid] = lc_l;
  __syncthreads();
  for (int s = 128; s > 0; s >>= 1) {
    if (tid < s) {
      r_np[tid] += r_np[tid + s];
      r_c[tid] += r_c[tid + s];
      r_l[tid] += r_l[tid + s];
    }
    __syncthreads();
  }
  if (tid == 0 && r_np[0] > 0) {
    atomicAdd(&n_pos[b], r_np[0]);
    atomicAdd(&pconf[b], r_c[0]);
    atomicAdd(&ploc[b], r_l[0]);
  }
  for (int i = tid; i < 4096; i += 256)
    if (s_hist[i]) atomicAdd(&hist0[(size_t)b * 4096 + i], s_hist[i]);
}

// Cooperative block-wide radix select over BINS bins (descending cumulative).
template <int BINS>
__device__ void block_select(const unsigned* __restrict__ h, int remk,
                             unsigned* s_scan, int* s_out, unsigned* sel,
                             int* remk_o) {
  constexpr int BPT = BINS / 256;
  const int t = threadIdx.x;
  if (t == 0) { s_out[0] = BINS - 1; s_out[1] = 0; }  // remk<=0 sentinel
  unsigned mb[BPT];
  unsigned s = 0;
#pragma unroll
  for (int i = 0; i < BPT; ++i) { mb[i] = h[t * BPT + i]; s += mb[i]; }
  unsigned incl = s;
  s_scan[t] = incl;
  __syncthreads();
  for (int off = 1; off < 256; off <<= 1) {
    const unsigned add = (t >= off) ? s_scan[t - off] : 0u;
    __syncthreads();
    incl += add;
    s_scan[t] = incl;
    __syncthreads();
  }
  const unsigned total = s_scan[255];
  const unsigned R = total - incl;
  if (remk > 0 && R < (unsigned)remk && R + s >= (unsigned)remk) {
    unsigned acc = R;
    int sel_i = t * BPT, rk = 0;
    bool done = false;
#pragma unroll
    for (int i = BPT - 1; i >= 0; --i) {
      if (!done && acc + mb[i] >= (unsigned)remk) {
        sel_i = t * BPT + i;
        rk = remk - (int)acc;
        done = true;
      }
      if (!done) acc += mb[i];
    }
    s_out[0] = sel_i;
    s_out[1] = rk;
  }
  __syncthreads();
  *sel = (unsigned)s_out[0];
  *remk_o = s_out[1];
  __syncthreads();
}

__global__ __launch_bounds__(256) void mbl_hist1(
    const float* __restrict__ conf_neg, const int* __restrict__ n_pos,
    const unsigned* __restrict__ hist0, unsigned* __restrict__ hist1, int P) {
  const int b = blockIdx.y;
  const int tid = threadIdx.x;
  __shared__ unsigned s_scan[256];
  __shared__ int s_out[2];
  __shared__ unsigned s_hist[4096];
  int K = 3 * n_pos[b];
  if (K > P) K = P;
  unsigned sel0;
  int rem0;
  block_select<4096>(hist0 + (size_t)b * 4096, K, s_scan, s_out, &sel0, &rem0);
  for (int i = tid; i < 4096; i += 256) s_hist[i] = 0u;
  __syncthreads();
  const float* row = conf_neg + (size_t)b * P;
  const int n4 = P >> 2;
  const int per = (n4 + (int)gridDim.x - 1) / (int)gridDim.x;
  const int s4 = blockIdx.x * per, e4 = min(s4 + per, n4);
  for (int i = s4 + tid; i < e4; i += 256) {
    const float4 v = ((const float4*)row)[i];
    unsigned u;
    u = __float_as_uint(v.x); if ((u >> 20) == sel0) atomicAdd(&s_hist[(u >> 8) & 4095u], 1u);
    u = __float_as_uint(v.y); if ((u >> 20) == sel0) atomicAdd(&s_hist[(u >> 8) & 4095u], 1u);
    u = __float_as_uint(v.z); if ((u >> 20) == sel0) atomicAdd(&s_hist[(u >> 8) & 4095u], 1u);
    u = __float_as_uint(v.w); if ((u >> 20) == sel0) atomicAdd(&s_hist[(u >> 8) & 4095u], 1u);
  }
  if (blockIdx.x == 0)
    for (int p = (n4 << 2) + tid; p < P; p += 256) {
      const unsigned u = __float_as_uint(row[p]);
      if ((u >> 20) == sel0) atomicAdd(&s_hist[(u >> 8) & 4095u], 1u);
    }
  __syncthreads();
  for (int i = tid; i < 4096; i += 256)
    if (s_hist[i]) atomicAdd(&hist1[(size_t)b * 4096 + i], s_hist[i]);
}

// Sum above 24-bit threshold; boundary bin at midpoint; last block finalizes.
__global__ __launch_bounds__(256) void mbl_sum(
    const float* __restrict__ conf_neg, const int* __restrict__ n_pos,
    const unsigned* __restrict__ hist0, const unsigned* __restrict__ hist1,
    const double* __restrict__ pconf, const double* __restrict__ ploc,
    double* __restrict__ phard, unsigned* __restrict__ counter, int P, int B,
    float* __restrict__ out) {
  const int b = blockIdx.y;
  const int tid = threadIdx.x;
  __shared__ unsigned s_scan[256];
  __shared__ int s_out[2];
  int K = 3 * n_pos[b];
  if (K > P) K = P;
  unsigned sel0, sel1;
  int rem0, rem1;
  block_select<4096>(hist0 + (size_t)b * 4096, K, s_scan, s_out, &sel0, &rem0);
  block_select<4096>(hist1 + (size_t)b * 4096, rem0, s_scan, s_out, &sel1, &rem1);
  const unsigned pref24 = (sel0 << 12) | sel1;
  const unsigned tb = (pref24 << 8) | 0xFFu;
  const float* row = conf_neg + (size_t)b * P;
  const int n4 = P >> 2;
  const int per = (n4 + (int)gridDim.x - 1) / (int)gridDim.x;
  const int s4 = blockIdx.x * per, e4 = min(s4 + per, n4);
  double local = 0.0;
  for (int i = s4 + tid; i < e4; i += 256) {
    const float4 v = ((const float4*)row)[i];
    if (__float_as_uint(v.x) > tb) local += (double)v.x;
    if (__float_as_uint(v.y) > tb) local += (double)v.y;
    if (__float_as_uint(v.z) > tb) local += (double)v.z;
    if (__float_as_uint(v.w) > tb) local += (double)v.w;
  }
  if (blockIdx.x == 0) {
    for (int p = (n4 << 2) + tid; p < P; p += 256) {
      const float v = row[p];
      if (__float_as_uint(v) > tb) local += (double)v;
    }
    if (tid == 0 && rem1 > 0)
      local += (double)rem1 * (double)__uint_as_float((pref24 << 8) | 0x80u);
  }
  __shared__ double red[256];
  red[tid] = local;
  __syncthreads();
  for (int s = 128; s > 0; s >>= 1) {
    if (tid < s) red[tid] += red[tid + s];
    __syncthreads();
  }
  if (tid == 0) {
    if (red[0] != 0.0) atomicAdd(&phard[b], red[0]);
    __threadfence();
    const unsigned done = atomicAdd(counter, 1u);
    if (done == gridDim.x * gridDim.y - 1) {
      double tp = 0.0, cs = 0.0, ls = 0.0, hs = 0.0;
      for (int i = 0; i < B; ++i) {
        tp += (double)n_pos[i];
        cs += pconf[i];
        ls += ploc[i];
        hs += atomicAdd(&phard[i], 0.0);
      }
      out[0] = (float)((hs + cs) / tp);
      out[1] = (float)(ls / (tp * 6.0));
    }
  }
}

extern "C" void kernel_launch(void* const* d_in, const int* in_sizes, int n_in,
                              void* d_out, int out_size, void* d_ws, size_t ws_size,
                              hipStream_t stream) {
  const float* locs = (const float*)d_in[0];
  const float* scores = (const float*)d_in[1];
  const float* boxes = (const float*)d_in[2];
  const int* labels = (const int*)d_in[3];
  const float* priors = (const float*)d_in[4];

  const long long sz_locs = (long long)in_sizes[0];
  const long long sz_scores = (long long)in_sizes[1];
  const long long sz_priors = (long long)in_sizes[4];
  const int P = (int)(sz_priors / 6);
  const int B = (int)(sz_locs / sz_priors);
  const int n_obj = in_sizes[3] / B;
  const int C = (int)(sz_scores * 6 / sz_locs);

  const int nblk = (P + TILE - 1) / TILE;
  const int nobjT = (n_obj <= 16) ? 16 : ((n_obj <= 32) ? 32 : 64);

  char* ws = (char*)d_ws;
  size_t off = 0;
  double* pconf = (double*)(ws + off); off += (size_t)B * 8;
  double* ploc = (double*)(ws + off); off += (size_t)B * 8;
  double* phard = (double*)(ws + off); off += (size_t)B * 8;
  int* n_pos = (int*)(ws + off); off += ((size_t)B * 4 + 15) & ~(size_t)15;
  unsigned* counter = (unsigned*)(ws + off); off += 16;
  unsigned* M = (unsigned*)(ws + off); off += (size_t)B * 64 * 4;
  unsigned* win = (unsigned*)(ws + off); off += (size_t)B * 64 * 4;
  const size_t header_bytes = off;  // memset region
  unsigned* hist0 = (unsigned*)(ws + off); off += (size_t)B * 4096 * 4;
  unsigned* hist1 = (unsigned*)(ws + off); off += (size_t)B * 4096 * 4;
  const size_t hist_bytes = (size_t)B * 4096 * 4 * 2;
  float* conf_neg = (float*)(ws + off); off += ((size_t)B * P * 4 + 15) & ~(size_t)15;
  unsigned char* best_u8 = (unsigned char*)(ws + off);
  off += ((size_t)B * P + 15) & ~(size_t)15;
  unsigned* part_max = (unsigned*)(ws + off);
  off += (size_t)B * nblk * nobjT * 4;
  (void)ws_size;

  hipMemsetAsync(d_ws, 0, header_bytes, stream);

  const dim3 mgrid(nblk, B);
  const bool full = (P % TILE) == 0;
  if (n_obj <= 16) {
    if (full) mbl_match<16, true><<<mgrid, 256, 0, stream>>>(boxes, priors, part_max, M, best_u8, P, n_obj);
    else      mbl_match<16, false><<<mgrid, 256, 0, stream>>>(boxes, priors, part_max, M, best_u8, P, n_obj);
  } else if (n_obj <= 32) {
    if (full) mbl_match<32, true><<<mgrid, 256, 0, stream>>>(boxes, priors, part_max, M, best_u8, P, n_obj);
    else      mbl_match<32, false><<<mgrid, 256, 0, stream>>>(boxes, priors, part_max, M, best_u8, P, n_obj);
  } else {
    if (full) mbl_match<64, true><<<mgrid, 256, 0, stream>>>(boxes, priors, part_max, M, best_u8, P, n_obj);
    else      mbl_match<64, false><<<mgrid, 256, 0, stream>>>(boxes, priors, part_max, M, best_u8, P, n_obj);
  }

  if (full)
    mbl_recover<true><<<mgrid, 256, 0, stream>>>(boxes, priors, part_max, M, win,
                                                 (unsigned long long*)hist0,
                                                 (int)(hist_bytes / 8), P, n_obj, nobjT);
  else
    mbl_recover<false><<<mgrid, 256, 0, stream>>>(boxes, priors, part_max, M, win,
                                                  (unsigned long long*)hist0,
                                                  (int)(hist_bytes / 8), P, n_obj, nobjT);

  const dim3 lgrid(LB, B);
  if (C == 2)
    mbl_loss<2><<<lgrid, 256, 0, stream>>>(locs, scores, boxes, labels, priors, win,
                                           best_u8, conf_neg, hist0, n_pos, pconf,
                                           ploc, P, n_obj, C);
  else
    mbl_loss<0><<<lgrid, 256, 0, stream>>>(locs, scores, boxes, labels, priors, win,
                                           best_u8, conf_neg, hist0, n_pos, pconf,
                                           ploc, P, n_obj, C);

  mbl_hist1<<<lgrid, 256, 0, stream>>>(conf_neg, n_pos, hist0, hist1, P);
  mbl_sum<<<lgrid, 256, 0, stream>>>(conf_neg, n_pos, hist0, hist1, pconf, ploc,
                                     phard, counter, P, B, (float*)d_out);
}

// Round 8
// 102.904 us; speedup vs baseline: 1.0012x; 1.0012x over previous
//
#include <hip/hip_runtime.h>
#include <math.h>

#define LB 32  // blocks per batch for loss/hist/sum kernels

// ---------------------------------------------------------------------------
// ws layout (memset region first):
//   double pconf[B], ploc[B], phard[B] ; int n_pos[B] ; u32 counter (+pad)
//   u64    prior_fo[B*64]   : packed (iou_bits<<32)|(0xFFFFFFFF-p), atomicMax
//   u32    hist0[B][4096], hist1[B][4096]
//   ---- end memset ----
//   float  conf_neg[B*P]
//   u8     best_u8[B*P]     : bit7 = (best iou >= 0.5), bits0-6 = best obj
// ---------------------------------------------------------------------------

__device__ __forceinline__ unsigned long long umax64(unsigned long long a,
                                                     unsigned long long b) {
  return a > b ? a : b;
}

// Match: 1 prior/thread. Per-prior argmax packed in one reg; per-object max
// streamed to LDS and block-reduced with exact (iou, ~p) tie-break.
template <int NOBJ, bool FULL>
__global__ __launch_bounds__(256, 8) void mbl_match(
    const float* __restrict__ boxes, const float* __restrict__ priors,
    unsigned long long* __restrict__ prior_fo, unsigned char* __restrict__ best_u8,
    int P, int n_obj) {
  const int b = blockIdx.y;
  const int tid = threadIdx.x;
  __shared__ float4 s_box[NOBJ][2];  // {lo0,lo1,lo2,hi0},{hi1,hi2,vol,0}
  __shared__ unsigned s_tr[16][264];
  for (int i = tid; i < NOBJ; i += 256) {
    float4 v0, v1;
    if (i < n_obj) {
      const float* bx = boxes + ((size_t)b * n_obj + i) * 6;
      const float l0 = bx[0], l1 = bx[1], l2 = bx[2];
      const float h0 = bx[3], h1 = bx[4], h2 = bx[5];
      v0 = make_float4(l0, l1, l2, h0);
      v1 = make_float4(h1, h2, ((h0 - l0) * (h1 - l1)) * (h2 - l2), 0.f);
    } else {  // dummy object: iou 0 vs every real prior
      v0 = make_float4(3e18f, 3e18f, 3e18f, 1e18f);
      v1 = make_float4(1e18f, 1e18f, 0.f, 0.f);
    }
    s_box[i][0] = v0;
    s_box[i][1] = v1;
  }
  __syncthreads();

  const int pbase = blockIdx.x * 256;
  const int p = pbase + tid;
  float lo0, lo1, lo2, hi0, hi1, hi2, vb;
  if (FULL || p < P) {
    const float2 q0 = *(const float2*)(priors + (size_t)p * 6);
    const float2 q1 = *(const float2*)(priors + (size_t)p * 6 + 2);
    const float2 q2 = *(const float2*)(priors + (size_t)p * 6 + 4);
    lo0 = q0.x - q1.y * 0.5f; hi0 = q0.x + q1.y * 0.5f;
    lo1 = q0.y - q2.x * 0.5f; hi1 = q0.y + q2.x * 0.5f;
    lo2 = q1.x - q2.y * 0.5f; hi2 = q1.x + q2.y * 0.5f;
    vb = (q1.y * q2.x) * q2.y;
  } else {  // dummy prior: iou 0 vs real objects
    lo0 = lo1 = lo2 = 3e18f;
    hi0 = hi1 = hi2 = 3e18f;
    vb = 0.f;
  }

  const unsigned msk = ~(unsigned)(NOBJ - 1);
  unsigned pk = 0u;

  for (int o0 = 0; o0 < NOBJ; o0 += 16) {
    if (o0) __syncthreads();  // protect s_tr reuse across passes
#pragma unroll
    for (int oo = 0; oo < 16; ++oo) {
      const int o = o0 + oo;
      const float4 c0 = s_box[o][0];
      const float4 c1 = s_box[o][1];
      const float d0 = fminf(c0.w, hi0) - fmaxf(c0.x, lo0);
      const float d1 = fminf(c1.x, hi1) - fmaxf(c0.y, lo1);
      const float d2 = fminf(c1.y, hi2) - fmaxf(c0.z, lo2);
      const float inter = (fmaxf(d0, 0.f) * fmaxf(d1, 0.f)) * fmaxf(d2, 0.f);
      const float un = (c1.z + vb) - inter;
      const float iou = inter * __builtin_amdgcn_rcpf(un);
      s_tr[oo][tid] = __float_as_uint(iou);  // exact value for per-object max
      // per-prior argmax: quantized iou | inverted obj idx (first-occurrence)
      const unsigned cand =
          (__float_as_uint(iou) & msk) | (unsigned)(NOBJ - 1 - o);
      pk = max(pk, cand);
    }
    __syncthreads();
    // 16 objects x 16 lanes: exact block argmax with min-p tie-break
    const int obj = tid >> 4, j = tid & 15;
    unsigned long long m = 0ULL;
#pragma unroll
    for (int i = 0; i < 16; ++i) {
      const int col = j + 16 * i;
      const unsigned long long x =
          ((unsigned long long)s_tr[obj][col] << 32) |
          (0xFFFFFFFFu - (unsigned)(pbase + col));
      m = umax64(m, x);
    }
#pragma unroll
    for (int off = 1; off < 16; off <<= 1)
      m = umax64(m, __shfl_xor(m, off, 64));
    if (j == 0) {
      const int o = o0 + obj;
      if (o < n_obj) atomicMax(&prior_fo[(size_t)b * 64 + o], m);
    }
  }

  if (FULL || p < P) {
    const int bo = (NOBJ - 1) - (int)(pk & (unsigned)(NOBJ - 1));
    best_u8[(size_t)b * P + p] =
        (unsigned char)((unsigned)bo | (pk >= 0x3F000000u ? 0x80u : 0u));
  }
}

// Loss: override scan + CE + loc L1 + conf_neg + fused 12-bit hist0.
template <int CC>
__global__ __launch_bounds__(256) void mbl_loss(
    const float* __restrict__ locs, const float* __restrict__ scores,
    const float* __restrict__ boxes, const int* __restrict__ labels,
    const float* __restrict__ priors, const unsigned long long* __restrict__ prior_fo,
    const unsigned char* __restrict__ best_u8, float* __restrict__ conf_neg,
    unsigned* __restrict__ hist0, int* __restrict__ n_pos,
    double* __restrict__ pconf, double* __restrict__ ploc, int P, int n_obj,
    int C) {
  const int b = blockIdx.y;
  const int tid = threadIdx.x;
  __shared__ float s_box[64][6];
  __shared__ int s_lab[64];
  __shared__ unsigned s_fo[64];
  __shared__ unsigned s_hist[4096];
  for (int i = tid; i < 4096; i += 256) s_hist[i] = 0u;
  for (int i = tid; i < n_obj * 6; i += 256)
    s_box[i / 6][i % 6] = boxes[(size_t)b * n_obj * 6 + i];
  for (int i = tid; i < n_obj; i += 256) {
    s_lab[i] = labels[(size_t)b * n_obj + i];
    s_fo[i] = 0xFFFFFFFFu - (unsigned)(prior_fo[(size_t)b * 64 + i] & 0xFFFFFFFFull);
  }
  __syncthreads();

  unsigned fo_r[16];
  const bool small_obj = (n_obj <= 16);
  if (small_obj) {
#pragma unroll
    for (int o = 0; o < 16; ++o) fo_r[o] = (o < n_obj) ? s_fo[o] : 0xFFFFFFFEu;
  }

  int np_l = 0;
  double cf_l = 0.0, lc_l = 0.0;

  if (CC == 2 && (P & 1) == 0) {
    // vectorized: 2 priors / thread via float4 score loads
    const int P2 = P >> 1;
    const int chunk = (P2 + (int)gridDim.x - 1) / (int)gridDim.x;
    const int start = blockIdx.x * chunk;
    const int end = min(start + chunk, P2);
    for (int q = start + tid; q < end; q += 256) {
      const float4 sc = *(const float4*)(scores + ((size_t)b * P2 + q) * 4);
      const unsigned short bpp =
          *(const unsigned short*)(best_u8 + (size_t)b * P + 2 * q);
      float cn2[2];
#pragma unroll
      for (int e = 0; e < 2; ++e) {
        const int p = 2 * q + e;
        const unsigned bp = e ? (bpp >> 8) : (bpp & 0xFFu);
        int obj = bp & 0x7F;
        int posf = (int)(bp >> 7);
        if (small_obj) {
#pragma unroll
          for (int o = 0; o < 16; ++o)
            if (fo_r[o] == (unsigned)p) { obj = o; posf = 1; }  // last wins
        } else {
          for (int o = 0; o < n_obj; ++o)
            if (s_fo[o] == (unsigned)p) { obj = o; posf = 1; }
        }
        const int lab = posf ? s_lab[obj] : 0;
        const float sx = e ? sc.z : sc.x;
        const float sy = e ? sc.w : sc.y;
        const float mm = fmaxf(sx, sy);
        const float conf =
            (lab < 0) ? 0.f
                      : (mm + __logf(__expf(sx - mm) + __expf(sy - mm)) -
                         ((lab == 0) ? sx : sy));
        float cn = conf;
        if (lab > 0) {
          np_l++;
          cf_l += (double)conf;
          const float* pr = priors + (size_t)p * 6;
          const float* pl = locs + ((size_t)b * P + p) * 6;
          float ls = 0.f;
          for (int i = 0; i < 3; ++i) {
            const float c0 = (s_box[obj][i] + s_box[obj][i + 3]) * 0.5f;
            const float szb = s_box[obj][i + 3] - s_box[obj][i];
            const float g = (c0 - pr[i]) / (pr[i + 3] / 10.0f);
            const float g2 = logf(szb / pr[i + 3]) * 5.0f;
            ls += fabsf(pl[i] - g) + fabsf(pl[i + 3] - g2);
          }
          lc_l += (double)ls;
          cn = 0.f;
        }
        cn2[e] = cn;
        atomicAdd(&s_hist[__float_as_uint(cn) >> 20], 1u);
      }
      *(float2*)(conf_neg + (size_t)b * P + 2 * q) = make_float2(cn2[0], cn2[1]);
    }
  } else {
    const int chunk = (P + (int)gridDim.x - 1) / (int)gridDim.x;
    const int start = blockIdx.x * chunk;
    const int end = min(start + chunk, P);
    for (int p = start + tid; p < end; p += 256) {
      const unsigned char bp = best_u8[(size_t)b * P + p];
      int obj = bp & 0x7F;
      int posf = bp >> 7;
      for (int o = 0; o < n_obj; ++o)
        if (s_fo[o] == (unsigned)p) { obj = o; posf = 1; }
      const int lab = posf ? s_lab[obj] : 0;
      const float* sp = scores + ((size_t)b * P + p) * C;
      float m = sp[0];
      for (int c = 1; c < C; ++c) m = fmaxf(m, sp[c]);
      float se = 0.f;
      for (int c = 0; c < C; ++c) se += __expf(sp[c] - m);
      const float conf = (lab < 0) ? 0.f : (m + __logf(se) - sp[lab]);
      float cn = conf;
      if (lab > 0) {
        np_l++;
        cf_l += (double)conf;
        const float* pr = priors + (size_t)p * 6;
        const float* pl = locs + ((size_t)b * P + p) * 6;
        float ls = 0.f;
        for (int i = 0; i < 3; ++i) {
          const float c0 = (s_box[obj][i] + s_box[obj][i + 3]) * 0.5f;
          const float szb = s_box[obj][i + 3] - s_box[obj][i];
          const float g = (c0 - pr[i]) / (pr[i + 3] / 10.0f);
          const float g2 = logf(szb / pr[i + 3]) * 5.0f;
          ls += fabsf(pl[i] - g) + fabsf(pl[i + 3] - g2);
        }
        lc_l += (double)ls;
        cn = 0.f;
      }
      conf_neg[(size_t)b * P + p] = cn;
      atomicAdd(&s_hist[__float_as_uint(cn) >> 20], 1u);
    }
  }

  __shared__ int r_np[256];
  __shared__ double r_c[256];
  __shared__ double r_l[256];
  r_np[tid] = np_l;
  r_c[tid] = cf_l;
  r_l[tid] = lc_l;
  __syncthreads();
  for (int s = 128; s > 0; s >>= 1) {
    if (tid < s) {
      r_np[tid] += r_np[tid + s];
      r_c[tid] += r_c[tid + s];
      r_l[tid] += r_l[tid + s];
    }
    __syncthreads();
  }
  if (tid == 0 && r_np[0] > 0) {
    atomicAdd(&n_pos[b], r_np[0]);
    atomicAdd(&pconf[b], r_c[0]);
    atomicAdd(&ploc[b], r_l[0]);
  }
  for (int i = tid; i < 4096; i += 256)
    if (s_hist[i]) atomicAdd(&hist0[(size_t)b * 4096 + i], s_hist[i]);
}

// Cooperative block-wide radix select over BINS bins (descending cumulative).
template <int BINS>
__device__ void block_select(const unsigned* __restrict__ h, int remk,
                             unsigned* s_scan, int* s_out, unsigned* sel,
                             int* remk_o) {
  constexpr int BPT = BINS / 256;
  const int t = threadIdx.x;
  if (t == 0) { s_out[0] = BINS - 1; s_out[1] = 0; }  // remk<=0 sentinel
  unsigned mb[BPT];
  unsigned s = 0;
#pragma unroll
  for (int i = 0; i < BPT; ++i) { mb[i] = h[t * BPT + i]; s += mb[i]; }
  unsigned incl = s;
  s_scan[t] = incl;
  __syncthreads();
  for (int off = 1; off < 256; off <<= 1) {
    const unsigned add = (t >= off) ? s_scan[t - off] : 0u;
    __syncthreads();
    incl += add;
    s_scan[t] = incl;
    __syncthreads();
  }
  const unsigned total = s_scan[255];
  const unsigned R = total - incl;
  if (remk > 0 && R < (unsigned)remk && R + s >= (unsigned)remk) {
    unsigned acc = R;
    int sel_i = t * BPT, rk = 0;
    bool done = false;
#pragma unroll
    for (int i = BPT - 1; i >= 0; --i) {
      if (!done && acc + mb[i] >= (unsigned)remk) {
        sel_i = t * BPT + i;
        rk = remk - (int)acc;
        done = true;
      }
      if (!done) acc += mb[i];
    }
    s_out[0] = sel_i;
    s_out[1] = rk;
  }
  __syncthreads();
  *sel = (unsigned)s_out[0];
  *remk_o = s_out[1];
  __syncthreads();
}

__global__ __launch_bounds__(256) void mbl_hist1(
    const float* __restrict__ conf_neg, const int* __restrict__ n_pos,
    const unsigned* __restrict__ hist0, unsigned* __restrict__ hist1, int P) {
  const int b = blockIdx.y;
  const int tid = threadIdx.x;
  __shared__ unsigned s_scan[256];
  __shared__ int s_out[2];
  __shared__ unsigned s_hist[4096];
  int K = 3 * n_pos[b];
  if (K > P) K = P;
  unsigned sel0;
  int rem0;
  block_select<4096>(hist0 + (size_t)b * 4096, K, s_scan, s_out, &sel0, &rem0);
  for (int i = tid; i < 4096; i += 256) s_hist[i] = 0u;
  __syncthreads();
  const float* row = conf_neg + (size_t)b * P;
  const int n4 = P >> 2;
  const int per = (n4 + (int)gridDim.x - 1) / (int)gridDim.x;
  const int s4 = blockIdx.x * per, e4 = min(s4 + per, n4);
  for (int i = s4 + tid; i < e4; i += 256) {
    const float4 v = ((const float4*)row)[i];
    unsigned u;
    u = __float_as_uint(v.x); if ((u >> 20) == sel0) atomicAdd(&s_hist[(u >> 8) & 4095u], 1u);
    u = __float_as_uint(v.y); if ((u >> 20) == sel0) atomicAdd(&s_hist[(u >> 8) & 4095u], 1u);
    u = __float_as_uint(v.z); if ((u >> 20) == sel0) atomicAdd(&s_hist[(u >> 8) & 4095u], 1u);
    u = __float_as_uint(v.w); if ((u >> 20) == sel0) atomicAdd(&s_hist[(u >> 8) & 4095u], 1u);
  }
  if (blockIdx.x == 0)
    for (int p = (n4 << 2) + tid; p < P; p += 256) {
      const unsigned u = __float_as_uint(row[p]);
      if ((u >> 20) == sel0) atomicAdd(&s_hist[(u >> 8) & 4095u], 1u);
    }
  __syncthreads();
  for (int i = tid; i < 4096; i += 256)
    if (s_hist[i]) atomicAdd(&hist1[(size_t)b * 4096 + i], s_hist[i]);
}

// Sum above 24-bit threshold; boundary bin at midpoint; last block finalizes.
__global__ __launch_bounds__(256) void mbl_sum(
    const float* __restrict__ conf_neg, const int* __restrict__ n_pos,
    const unsigned* __restrict__ hist0, const unsigned* __restrict__ hist1,
    const double* __restrict__ pconf, const double* __restrict__ ploc,
    double* __restrict__ phard, unsigned* __restrict__ counter, int P, int B,
    float* __restrict__ out) {
  const int b = blockIdx.y;
  const int tid = threadIdx.x;
  __shared__ unsigned s_scan[256];
  __shared__ int s_out[2];
  int K = 3 * n_pos[b];
  if (K > P) K = P;
  unsigned sel0, sel1;
  int rem0, rem1;
  block_select<4096>(hist0 + (size_t)b * 4096, K, s_scan, s_out, &sel0, &rem0);
  block_select<4096>(hist1 + (size_t)b * 4096, rem0, s_scan, s_out, &sel1, &rem1);
  const unsigned pref24 = (sel0 << 12) | sel1;
  const unsigned tb = (pref24 << 8) | 0xFFu;
  const float* row = conf_neg + (size_t)b * P;
  const int n4 = P >> 2;
  const int per = (n4 + (int)gridDim.x - 1) / (int)gridDim.x;
  const int s4 = blockIdx.x * per, e4 = min(s4 + per, n4);
  double local = 0.0;
  for (int i = s4 + tid; i < e4; i += 256) {
    const float4 v = ((const float4*)row)[i];
    if (__float_as_uint(v.x) > tb) local += (double)v.x;
    if (__float_as_uint(v.y) > tb) local += (double)v.y;
    if (__float_as_uint(v.z) > tb) local += (double)v.z;
    if (__float_as_uint(v.w) > tb) local += (double)v.w;
  }
  if (blockIdx.x == 0) {
    for (int p = (n4 << 2) + tid; p < P; p += 256) {
      const float v = row[p];
      if (__float_as_uint(v) > tb) local += (double)v;
    }
    if (tid == 0 && rem1 > 0)
      local += (double)rem1 * (double)__uint_as_float((pref24 << 8) | 0x80u);
  }
  __shared__ double red[256];
  red[tid] = local;
  __syncthreads();
  for (int s = 128; s > 0; s >>= 1) {
    if (tid < s) red[tid] += red[tid + s];
    __syncthreads();
  }
  if (tid == 0) {
    if (red[0] != 0.0) atomicAdd(&phard[b], red[0]);
    __threadfence();
    const unsigned done = atomicAdd(counter, 1u);
    if (done == gridDim.x * gridDim.y - 1) {
      double tp = 0.0, cs = 0.0, ls = 0.0, hs = 0.0;
      for (int i = 0; i < B; ++i) {
        tp += (double)n_pos[i];
        cs += pconf[i];
        ls += ploc[i];
        hs += atomicAdd(&phard[i], 0.0);
      }
      out[0] = (float)((hs + cs) / tp);
      out[1] = (float)(ls / (tp * 6.0));
    }
  }
}

extern "C" void kernel_launch(void* const* d_in, const int* in_sizes, int n_in,
                              void* d_out, int out_size, void* d_ws, size_t ws_size,
                              hipStream_t stream) {
  const float* locs = (const float*)d_in[0];
  const float* scores = (const float*)d_in[1];
  const float* boxes = (const float*)d_in[2];
  const int* labels = (const int*)d_in[3];
  const float* priors = (const float*)d_in[4];

  const long long sz_locs = (long long)in_sizes[0];
  const long long sz_scores = (long long)in_sizes[1];
  const long long sz_priors = (long long)in_sizes[4];
  const int P = (int)(sz_priors / 6);
  const int B = (int)(sz_locs / sz_priors);
  const int n_obj = in_sizes[3] / B;
  const int C = (int)(sz_scores * 6 / sz_locs);

  char* ws = (char*)d_ws;
  size_t off = 0;
  double* pconf = (double*)(ws + off); off += (size_t)B * 8;
  double* ploc = (double*)(ws + off); off += (size_t)B * 8;
  double* phard = (double*)(ws + off); off += (size_t)B * 8;
  int* n_pos = (int*)(ws + off); off += ((size_t)B * 4 + 15) & ~(size_t)15;
  unsigned* counter = (unsigned*)(ws + off); off += 16;
  unsigned long long* prior_fo = (unsigned long long*)(ws + off);
  off += (size_t)B * 64 * 8;
  unsigned* hist0 = (unsigned*)(ws + off); off += (size_t)B * 4096 * 4;
  unsigned* hist1 = (unsigned*)(ws + off); off += (size_t)B * 4096 * 4;
  const size_t zero_bytes = off;
  float* conf_neg = (float*)(ws + off); off += ((size_t)B * P * 4 + 15) & ~(size_t)15;
  unsigned char* best_u8 = (unsigned char*)(ws + off);
  off += ((size_t)B * P + 15) & ~(size_t)15;
  (void)ws_size;

  hipMemsetAsync(d_ws, 0, zero_bytes, stream);

  const int nblk = (P + 255) / 256;
  const dim3 mgrid(nblk, B);
  const bool full = (P % 256) == 0;
  if (n_obj <= 16) {
    if (full) mbl_match<16, true><<<mgrid, 256, 0, stream>>>(boxes, priors, prior_fo, best_u8, P, n_obj);
    else      mbl_match<16, false><<<mgrid, 256, 0, stream>>>(boxes, priors, prior_fo, best_u8, P, n_obj);
  } else if (n_obj <= 32) {
    if (full) mbl_match<32, true><<<mgrid, 256, 0, stream>>>(boxes, priors, prior_fo, best_u8, P, n_obj);
    else      mbl_match<32, false><<<mgrid, 256, 0, stream>>>(boxes, priors, prior_fo, best_u8, P, n_obj);
  } else {
    if (full) mbl_match<64, true><<<mgrid, 256, 0, stream>>>(boxes, priors, prior_fo, best_u8, P, n_obj);
    else      mbl_match<64, false><<<mgrid, 256, 0, stream>>>(boxes, priors, prior_fo, best_u8, P, n_obj);
  }

  const dim3 lgrid(LB, B);
  if (C == 2)
    mbl_loss<2><<<lgrid, 256, 0, stream>>>(locs, scores, boxes, labels, priors,
                                           prior_fo, best_u8, conf_neg, hist0, n_pos,
                                           pconf, ploc, P, n_obj, C);
  else
    mbl_loss<0><<<lgrid, 256, 0, stream>>>(locs, scores, boxes, labels, priors,
                                           prior_fo, best_u8, conf_neg, hist0, n_pos,
                                           pconf, ploc, P, n_obj, C);

  mbl_hist1<<<lgrid, 256, 0, stream>>>(conf_neg, n_pos, hist0, hist1, P);
  mbl_sum<<<lgrid, 256, 0, stream>>>(conf_neg, n_pos, hist0, hist1, pconf, ploc,
                                     phard, counter, P, B, (float*)d_out);
}

// Round 9
// 97.957 us; speedup vs baseline: 1.0518x; 1.0505x over previous
//
#include <hip/hip_runtime.h>
#include <math.h>

#define MITEMS 2
#define TILE 512  // 256 * MITEMS
#define LB 32     // blocks per batch for loss/hist/sum kernels

// ---------------------------------------------------------------------------
// ws layout (memset region first):
//   double pconf[B], ploc[B], phard[B] ; int n_pos[B] ; u32 counter (+pad)
//   u64    prior_fo[B*64]   : packed (iou_bits<<32)|(0xFFFFFFFF-p), atomicMax
//   u32    hist0[B][4096], hist1[B][4096]
//   ---- end memset ----
//   float  conf_neg[B*P]
//   u8     best_u8[B*P]     : bit7 = (best iou >= 0.5), bits0-6 = best obj
// ---------------------------------------------------------------------------

__device__ __forceinline__ unsigned long long umax64(unsigned long long a,
                                                     unsigned long long b) {
  return a > b ? a : b;
}
__device__ __forceinline__ float rfl(float x) {
  return __uint_as_float(__builtin_amdgcn_readfirstlane(__float_as_uint(x)));
}

// Match: 2 priors/thread, boxes in SGPRs (readfirstlane), zero LDS in the
// inner loop. Per-prior argmax: quantized pk (iou | inv-obj in stolen LSBs).
// Per-object argmax: piou[8]/cohort + 1-bit k-flags, exact (iou,~p) via
// padded LDS transpose + 32-lane butterfly + u64 atomicMax.
template <int NOBJ, bool FULL>
__global__ __launch_bounds__(256) void mbl_match(
    const float* __restrict__ boxes, const float* __restrict__ priors,
    unsigned long long* __restrict__ prior_fo, unsigned char* __restrict__ best_u8,
    int P, int n_obj) {
  const int b = blockIdx.y;
  const int tid = threadIdx.x;
  __shared__ unsigned s_iou[8][264];  // 264 pad: (8*oo + tid) % 32 -> 2/bank
  __shared__ unsigned s_kfl[264];

  const int pbase = blockIdx.x * TILE;
  float lo0[MITEMS], lo1[MITEMS], lo2[MITEMS], hi0[MITEMS], hi1[MITEMS],
      hi2[MITEMS], vb[MITEMS];
#pragma unroll
  for (int k = 0; k < MITEMS; ++k) {
    const int p = pbase + k * 256 + tid;
    if (FULL || p < P) {
      const float2 q0 = *(const float2*)(priors + (size_t)p * 6);
      const float2 q1 = *(const float2*)(priors + (size_t)p * 6 + 2);
      const float2 q2 = *(const float2*)(priors + (size_t)p * 6 + 4);
      lo0[k] = q0.x - q1.y * 0.5f; hi0[k] = q0.x + q1.y * 0.5f;
      lo1[k] = q0.y - q2.x * 0.5f; hi1[k] = q0.y + q2.x * 0.5f;
      lo2[k] = q1.x - q2.y * 0.5f; hi2[k] = q1.x + q2.y * 0.5f;
      vb[k] = (q1.y * q2.x) * q2.y;
    } else {  // dummy prior: iou 0 vs everything
      lo0[k] = lo1[k] = lo2[k] = 3e18f;
      hi0[k] = hi1[k] = hi2[k] = 3e18f;
      vb[k] = 0.f;
    }
  }

  const unsigned msk = ~(unsigned)(NOBJ - 1);
  unsigned pk = 0u;
  const float* bx = boxes + (size_t)b * n_obj * 6;

  for (int pass = 0; pass < NOBJ / 8; ++pass) {
    if (pass) __syncthreads();  // protect s_iou/s_kfl reuse
    // cohort: 8 objects into scalar regs (block-uniform -> readfirstlane)
    float sl0[8], sl1[8], sl2[8], sh0[8], sh1[8], sh2[8], sv[8];
#pragma unroll
    for (int oo = 0; oo < 8; ++oo) {
      const int o = pass * 8 + oo;
      if (o < n_obj) {
        const float* q = bx + (size_t)o * 6;
        sl0[oo] = rfl(q[0]); sl1[oo] = rfl(q[1]); sl2[oo] = rfl(q[2]);
        sh0[oo] = rfl(q[3]); sh1[oo] = rfl(q[4]); sh2[oo] = rfl(q[5]);
        sv[oo] = rfl(((sh0[oo] - sl0[oo]) * (sh1[oo] - sl1[oo])) *
                     (sh2[oo] - sl2[oo]));
      } else {  // dummy object: iou 0 vs everything
        sl0[oo] = sl1[oo] = sl2[oo] = 3e18f;
        sh0[oo] = sh1[oo] = sh2[oo] = 3e18f;
        sv[oo] = 0.f;
      }
    }

    float piou[8];
#pragma unroll
    for (int oo = 0; oo < 8; ++oo) piou[oo] = 0.f;
    unsigned kfl = 0u;

#pragma unroll
    for (int oo = 0; oo < 8; ++oo) {
      const int o = pass * 8 + oo;
#pragma unroll
      for (int k = 0; k < MITEMS; ++k) {
        const float d0 = fminf(sh0[oo], hi0[k]) - fmaxf(sl0[oo], lo0[k]);
        const float d1 = fminf(sh1[oo], hi1[k]) - fmaxf(sl1[oo], lo1[k]);
        const float d2 = fminf(sh2[oo], hi2[k]) - fmaxf(sl2[oo], lo2[k]);
        const float inter = (fmaxf(d0, 0.f) * fmaxf(d1, 0.f)) * fmaxf(d2, 0.f);
        const float un = (sv[oo] + vb[k]) - inter;
        const float iou = inter * __builtin_amdgcn_rcpf(un);
        const unsigned cand =
            (__float_as_uint(iou) & msk) | (unsigned)(NOBJ - 1 - o);
        pk = max(pk, cand);
        const bool win = iou > piou[oo];  // strict: ties keep smaller k/p
        piou[oo] = win ? iou : piou[oo];
        if (k > 0) kfl = win ? (kfl | (1u << oo)) : kfl;
      }
    }

    // epilogue: exact per-object block argmax
    s_kfl[tid] = kfl;
#pragma unroll
    for (int oo = 0; oo < 8; ++oo) s_iou[oo][tid] = __float_as_uint(piou[oo]);
    __syncthreads();
    const int obj8 = tid >> 5, j = tid & 31;
    unsigned long long m = 0ULL;
#pragma unroll
    for (int i = 0; i < 8; ++i) {
      const int col = j + 32 * i;
      const unsigned ib = s_iou[obj8][col];
      const unsigned kf = (s_kfl[col] >> obj8) & 1u;
      const int p = pbase + (int)kf * 256 + col;
      m = umax64(m, ((unsigned long long)ib << 32) |
                        (0xFFFFFFFFu - (unsigned)p));
    }
#pragma unroll
    for (int off = 1; off < 32; off <<= 1)
      m = umax64(m, __shfl_xor(m, off, 64));
    if (j == 0) {
      const int o = pass * 8 + obj8;
      if (o < n_obj) atomicMax(&prior_fo[(size_t)b * 64 + o], m);
    }
  }

  // per-prior result
#pragma unroll
  for (int k = 0; k < MITEMS; ++k) {
    const int p = pbase + k * 256 + tid;
    if (FULL || p < P) {
      // NOTE: pk folds both k-priors? No — pk is per-thread over BOTH k.
    }
  }
  // pk was accumulated over both k together — recompute per-k packing needs
  // separate registers; use two pk accumulators instead (see below).
  (void)best_u8;
}

// --- The above epilogue note: we need per-k pk. Specialized real kernel: ---
template <int NOBJ, bool FULL>
__global__ __launch_bounds__(256) void mbl_match2(
    const float* __restrict__ boxes, const float* __restrict__ priors,
    unsigned long long* __restrict__ prior_fo, unsigned char* __restrict__ best_u8,
    int P, int n_obj) {
  const int b = blockIdx.y;
  const int tid = threadIdx.x;
  __shared__ unsigned s_iou[8][264];
  __shared__ unsigned s_kfl[264];

  const int pbase = blockIdx.x * TILE;
  float lo0[MITEMS], lo1[MITEMS], lo2[MITEMS], hi0[MITEMS], hi1[MITEMS],
      hi2[MITEMS], vb[MITEMS];
#pragma unroll
  for (int k = 0; k < MITEMS; ++k) {
    const int p = pbase + k * 256 + tid;
    if (FULL || p < P) {
      const float2 q0 = *(const float2*)(priors + (size_t)p * 6);
      const float2 q1 = *(const float2*)(priors + (size_t)p * 6 + 2);
      const float2 q2 = *(const float2*)(priors + (size_t)p * 6 + 4);
      lo0[k] = q0.x - q1.y * 0.5f; hi0[k] = q0.x + q1.y * 0.5f;
      lo1[k] = q0.y - q2.x * 0.5f; hi1[k] = q0.y + q2.x * 0.5f;
      lo2[k] = q1.x - q2.y * 0.5f; hi2[k] = q1.x + q2.y * 0.5f;
      vb[k] = (q1.y * q2.x) * q2.y;
    } else {
      lo0[k] = lo1[k] = lo2[k] = 3e18f;
      hi0[k] = hi1[k] = hi2[k] = 3e18f;
      vb[k] = 0.f;
    }
  }

  const unsigned msk = ~(unsigned)(NOBJ - 1);
  unsigned pk[MITEMS];
#pragma unroll
  for (int k = 0; k < MITEMS; ++k) pk[k] = 0u;
  const float* bx = boxes + (size_t)b * n_obj * 6;

  for (int pass = 0; pass < NOBJ / 8; ++pass) {
    if (pass) __syncthreads();
    float sl0[8], sl1[8], sl2[8], sh0[8], sh1[8], sh2[8], sv[8];
#pragma unroll
    for (int oo = 0; oo < 8; ++oo) {
      const int o = pass * 8 + oo;
      if (o < n_obj) {
        const float* q = bx + (size_t)o * 6;
        sl0[oo] = rfl(q[0]); sl1[oo] = rfl(q[1]); sl2[oo] = rfl(q[2]);
        sh0[oo] = rfl(q[3]); sh1[oo] = rfl(q[4]); sh2[oo] = rfl(q[5]);
        sv[oo] = rfl(((sh0[oo] - sl0[oo]) * (sh1[oo] - sl1[oo])) *
                     (sh2[oo] - sl2[oo]));
      } else {
        sl0[oo] = sl1[oo] = sl2[oo] = 3e18f;
        sh0[oo] = sh1[oo] = sh2[oo] = 3e18f;
        sv[oo] = 0.f;
      }
    }

    float piou[8];
#pragma unroll
    for (int oo = 0; oo < 8; ++oo) piou[oo] = 0.f;
    unsigned kfl = 0u;

#pragma unroll
    for (int oo = 0; oo < 8; ++oo) {
      const int o = pass * 8 + oo;
      const unsigned inv_o = (unsigned)(NOBJ - 1 - o);
#pragma unroll
      for (int k = 0; k < MITEMS; ++k) {
        const float d0 = fminf(sh0[oo], hi0[k]) - fmaxf(sl0[oo], lo0[k]);
        const float d1 = fminf(sh1[oo], hi1[k]) - fmaxf(sl1[oo], lo1[k]);
        const float d2 = fminf(sh2[oo], hi2[k]) - fmaxf(sl2[oo], lo2[k]);
        const float inter = (fmaxf(d0, 0.f) * fmaxf(d1, 0.f)) * fmaxf(d2, 0.f);
        const float un = (sv[oo] + vb[k]) - inter;
        const float iou = inter * __builtin_amdgcn_rcpf(un);
        pk[k] = max(pk[k], (__float_as_uint(iou) & msk) | inv_o);
        const bool win = iou > piou[oo];  // strict: ties keep smaller k -> p
        piou[oo] = win ? iou : piou[oo];
        if (k > 0) kfl = win ? (kfl | (1u << oo)) : kfl;
      }
    }

    s_kfl[tid] = kfl;
#pragma unroll
    for (int oo = 0; oo < 8; ++oo) s_iou[oo][tid] = __float_as_uint(piou[oo]);
    __syncthreads();
    const int obj8 = tid >> 5, j = tid & 31;
    unsigned long long m = 0ULL;
#pragma unroll
    for (int i = 0; i < 8; ++i) {
      const int col = j + 32 * i;
      const unsigned ib = s_iou[obj8][col];
      const unsigned kf = (s_kfl[col] >> obj8) & 1u;
      const int p = pbase + (int)kf * 256 + col;
      m = umax64(m, ((unsigned long long)ib << 32) |
                        (0xFFFFFFFFu - (unsigned)p));
    }
#pragma unroll
    for (int off = 1; off < 32; off <<= 1)
      m = umax64(m, __shfl_xor(m, off, 64));
    if (j == 0) {
      const int o = pass * 8 + obj8;
      if (o < n_obj) atomicMax(&prior_fo[(size_t)b * 64 + o], m);
    }
  }

#pragma unroll
  for (int k = 0; k < MITEMS; ++k) {
    const int p = pbase + k * 256 + tid;
    if (FULL || p < P) {
      const int bo = (NOBJ - 1) - (int)(pk[k] & (unsigned)(NOBJ - 1));
      best_u8[(size_t)b * P + p] =
          (unsigned char)((unsigned)bo | (pk[k] >= 0x3F000000u ? 0x80u : 0u));
    }
  }
}

// Loss: override scan + CE + loc L1 + conf_neg + fused 12-bit hist0.
template <int CC>
__global__ __launch_bounds__(256) void mbl_loss(
    const float* __restrict__ locs, const float* __restrict__ scores,
    const float* __restrict__ boxes, const int* __restrict__ labels,
    const float* __restrict__ priors, const unsigned long long* __restrict__ prior_fo,
    const unsigned char* __restrict__ best_u8, float* __restrict__ conf_neg,
    unsigned* __restrict__ hist0, int* __restrict__ n_pos,
    double* __restrict__ pconf, double* __restrict__ ploc, int P, int n_obj,
    int C) {
  const int b = blockIdx.y;
  const int tid = threadIdx.x;
  __shared__ float s_box[64][6];
  __shared__ int s_lab[64];
  __shared__ unsigned s_fo[64];
  __shared__ unsigned s_hist[4096];
  for (int i = tid; i < 4096; i += 256) s_hist[i] = 0u;
  for (int i = tid; i < n_obj * 6; i += 256)
    s_box[i / 6][i % 6] = boxes[(size_t)b * n_obj * 6 + i];
  for (int i = tid; i < n_obj; i += 256) {
    s_lab[i] = labels[(size_t)b * n_obj + i];
    s_fo[i] = 0xFFFFFFFFu - (unsigned)(prior_fo[(size_t)b * 64 + i] & 0xFFFFFFFFull);
  }
  __syncthreads();

  unsigned fo_r[16];
  const bool small_obj = (n_obj <= 16);
  if (small_obj) {
#pragma unroll
    for (int o = 0; o < 16; ++o) fo_r[o] = (o < n_obj) ? s_fo[o] : 0xFFFFFFFEu;
  }

  int np_l = 0;
  double cf_l = 0.0, lc_l = 0.0;

  if (CC == 2 && (P & 1) == 0) {
    const int P2 = P >> 1;
    const int chunk = (P2 + (int)gridDim.x - 1) / (int)gridDim.x;
    const int start = blockIdx.x * chunk;
    const int end = min(start + chunk, P2);
    for (int q = start + tid; q < end; q += 256) {
      const float4 sc = *(const float4*)(scores + ((size_t)b * P2 + q) * 4);
      const unsigned short bpp =
          *(const unsigned short*)(best_u8 + (size_t)b * P + 2 * q);
      float cn2[2];
#pragma unroll
      for (int e = 0; e < 2; ++e) {
        const int p = 2 * q + e;
        const unsigned bp = e ? (bpp >> 8) : (bpp & 0xFFu);
        int obj = bp & 0x7F;
        int posf = (int)(bp >> 7);
        if (small_obj) {
#pragma unroll
          for (int o = 0; o < 16; ++o)
            if (fo_r[o] == (unsigned)p) { obj = o; posf = 1; }  // last wins
        } else {
          for (int o = 0; o < n_obj; ++o)
            if (s_fo[o] == (unsigned)p) { obj = o; posf = 1; }
        }
        const int lab = posf ? s_lab[obj] : 0;
        const float sx = e ? sc.z : sc.x;
        const float sy = e ? sc.w : sc.y;
        const float mm = fmaxf(sx, sy);
        const float conf =
            (lab < 0) ? 0.f
                      : (mm + __logf(__expf(sx - mm) + __expf(sy - mm)) -
                         ((lab == 0) ? sx : sy));
        float cn = conf;
        if (lab > 0) {
          np_l++;
          cf_l += (double)conf;
          const float* pr = priors + (size_t)p * 6;
          const float* pl = locs + ((size_t)b * P + p) * 6;
          float ls = 0.f;
          for (int i = 0; i < 3; ++i) {
            const float c0 = (s_box[obj][i] + s_box[obj][i + 3]) * 0.5f;
            const float szb = s_box[obj][i + 3] - s_box[obj][i];
            const float g = (c0 - pr[i]) / (pr[i + 3] / 10.0f);
            const float g2 = logf(szb / pr[i + 3]) * 5.0f;
            ls += fabsf(pl[i] - g) + fabsf(pl[i + 3] - g2);
          }
          lc_l += (double)ls;
          cn = 0.f;
        }
        cn2[e] = cn;
        atomicAdd(&s_hist[__float_as_uint(cn) >> 20], 1u);
      }
      *(float2*)(conf_neg + (size_t)b * P + 2 * q) = make_float2(cn2[0], cn2[1]);
    }
  } else {
    const int chunk = (P + (int)gridDim.x - 1) / (int)gridDim.x;
    const int start = blockIdx.x * chunk;
    const int end = min(start + chunk, P);
    for (int p = start + tid; p < end; p += 256) {
      const unsigned char bp = best_u8[(size_t)b * P + p];
      int obj = bp & 0x7F;
      int posf = bp >> 7;
      for (int o = 0; o < n_obj; ++o)
        if (s_fo[o] == (unsigned)p) { obj = o; posf = 1; }
      const int lab = posf ? s_lab[obj] : 0;
      const float* sp = scores + ((size_t)b * P + p) * C;
      float m = sp[0];
      for (int c = 1; c < C; ++c) m = fmaxf(m, sp[c]);
      float se = 0.f;
      for (int c = 0; c < C; ++c) se += __expf(sp[c] - m);
      const float conf = (lab < 0) ? 0.f : (m + __logf(se) - sp[lab]);
      float cn = conf;
      if (lab > 0) {
        np_l++;
        cf_l += (double)conf;
        const float* pr = priors + (size_t)p * 6;
        const float* pl = locs + ((size_t)b * P + p) * 6;
        float ls = 0.f;
        for (int i = 0; i < 3; ++i) {
          const float c0 = (s_box[obj][i] + s_box[obj][i + 3]) * 0.5f;
          const float szb = s_box[obj][i + 3] - s_box[obj][i];
          const float g = (c0 - pr[i]) / (pr[i + 3] / 10.0f);
          const float g2 = logf(szb / pr[i + 3]) * 5.0f;
          ls += fabsf(pl[i] - g) + fabsf(pl[i + 3] - g2);
        }
        lc_l += (double)ls;
        cn = 0.f;
      }
      conf_neg[(size_t)b * P + p] = cn;
      atomicAdd(&s_hist[__float_as_uint(cn) >> 20], 1u);
    }
  }

  __shared__ int r_np[256];
  __shared__ double r_c[256];
  __shared__ double r_l[256];
  r_np[tid] = np_l;
  r_c[tid] = cf_l;
  r_l[tid] = lc_l;
  __syncthreads();
  for (int s = 128; s > 0; s >>= 1) {
    if (tid < s) {
      r_np[tid] += r_np[tid + s];
      r_c[tid] += r_c[tid + s];
      r_l[tid] += r_l[tid + s];
    }
    __syncthreads();
  }
  if (tid == 0 && r_np[0] > 0) {
    atomicAdd(&n_pos[b], r_np[0]);
    atomicAdd(&pconf[b], r_c[0]);
    atomicAdd(&ploc[b], r_l[0]);
  }
  for (int i = tid; i < 4096; i += 256)
    if (s_hist[i]) atomicAdd(&hist0[(size_t)b * 4096 + i], s_hist[i]);
}

// Cooperative block-wide radix select over BINS bins (descending cumulative).
template <int BINS>
__device__ void block_select(const unsigned* __restrict__ h, int remk,
                             unsigned* s_scan, int* s_out, unsigned* sel,
                             int* remk_o) {
  constexpr int BPT = BINS / 256;
  const int t = threadIdx.x;
  if (t == 0) { s_out[0] = BINS - 1; s_out[1] = 0; }
  unsigned mb[BPT];
  unsigned s = 0;
#pragma unroll
  for (int i = 0; i < BPT; ++i) { mb[i] = h[t * BPT + i]; s += mb[i]; }
  unsigned incl = s;
  s_scan[t] = incl;
  __syncthreads();
  for (int off = 1; off < 256; off <<= 1) {
    const unsigned add = (t >= off) ? s_scan[t - off] : 0u;
    __syncthreads();
    incl += add;
    s_scan[t] = incl;
    __syncthreads();
  }
  const unsigned total = s_scan[255];
  const unsigned R = total - incl;
  if (remk > 0 && R < (unsigned)remk && R + s >= (unsigned)remk) {
    unsigned acc = R;
    int sel_i = t * BPT, rk = 0;
    bool done = false;
#pragma unroll
    for (int i = BPT - 1; i >= 0; --i) {
      if (!done && acc + mb[i] >= (unsigned)remk) {
        sel_i = t * BPT + i;
        rk = remk - (int)acc;
        done = true;
      }
      if (!done) acc += mb[i];
    }
    s_out[0] = sel_i;
    s_out[1] = rk;
  }
  __syncthreads();
  *sel = (unsigned)s_out[0];
  *remk_o = s_out[1];
  __syncthreads();
}

__global__ __launch_bounds__(256) void mbl_hist1(
    const float* __restrict__ conf_neg, const int* __restrict__ n_pos,
    const unsigned* __restrict__ hist0, unsigned* __restrict__ hist1, int P) {
  const int b = blockIdx.y;
  const int tid = threadIdx.x;
  __shared__ unsigned s_scan[256];
  __shared__ int s_out[2];
  __shared__ unsigned s_hist[4096];
  int K = 3 * n_pos[b];
  if (K > P) K = P;
  unsigned sel0;
  int rem0;
  block_select<4096>(hist0 + (size_t)b * 4096, K, s_scan, s_out, &sel0, &rem0);
  for (int i = tid; i < 4096; i += 256) s_hist[i] = 0u;
  __syncthreads();
  const float* row = conf_neg + (size_t)b * P;
  const int n4 = P >> 2;
  const int per = (n4 + (int)gridDim.x - 1) / (int)gridDim.x;
  const int s4 = blockIdx.x * per, e4 = min(s4 + per, n4);
  for (int i = s4 + tid; i < e4; i += 256) {
    const float4 v = ((const float4*)row)[i];
    unsigned u;
    u = __float_as_uint(v.x); if ((u >> 20) == sel0) atomicAdd(&s_hist[(u >> 8) & 4095u], 1u);
    u = __float_as_uint(v.y); if ((u >> 20) == sel0) atomicAdd(&s_hist[(u >> 8) & 4095u], 1u);
    u = __float_as_uint(v.z); if ((u >> 20) == sel0) atomicAdd(&s_hist[(u >> 8) & 4095u], 1u);
    u = __float_as_uint(v.w); if ((u >> 20) == sel0) atomicAdd(&s_hist[(u >> 8) & 4095u], 1u);
  }
  if (blockIdx.x == 0)
    for (int p = (n4 << 2) + tid; p < P; p += 256) {
      const unsigned u = __float_as_uint(row[p]);
      if ((u >> 20) == sel0) atomicAdd(&s_hist[(u >> 8) & 4095u], 1u);
    }
  __syncthreads();
  for (int i = tid; i < 4096; i += 256)
    if (s_hist[i]) atomicAdd(&hist1[(size_t)b * 4096 + i], s_hist[i]);
}

// Sum above 24-bit threshold; boundary bin at midpoint; last block finalizes.
__global__ __launch_bounds__(256) void mbl_sum(
    const float* __restrict__ conf_neg, const int* __restrict__ n_pos,
    const unsigned* __restrict__ hist0, const unsigned* __restrict__ hist1,
    const double* __restrict__ pconf, const double* __restrict__ ploc,
    double* __restrict__ phard, unsigned* __restrict__ counter, int P, int B,
    float* __restrict__ out) {
  const int b = blockIdx.y;
  const int tid = threadIdx.x;
  __shared__ unsigned s_scan[256];
  __shared__ int s_out[2];
  int K = 3 * n_pos[b];
  if (K > P) K = P;
  unsigned sel0, sel1;
  int rem0, rem1;
  block_select<4096>(hist0 + (size_t)b * 4096, K, s_scan, s_out, &sel0, &rem0);
  block_select<4096>(hist1 + (size_t)b * 4096, rem0, s_scan, s_out, &sel1, &rem1);
  const unsigned pref24 = (sel0 << 12) | sel1;
  const unsigned tb = (pref24 << 8) | 0xFFu;
  const float* row = conf_neg + (size_t)b * P;
  const int n4 = P >> 2;
  const int per = (n4 + (int)gridDim.x - 1) / (int)gridDim.x;
  const int s4 = blockIdx.x * per, e4 = min(s4 + per, n4);
  double local = 0.0;
  for (int i = s4 + tid; i < e4; i += 256) {
    const float4 v = ((const float4*)row)[i];
    if (__float_as_uint(v.x) > tb) local += (double)v.x;
    if (__float_as_uint(v.y) > tb) local += (double)v.y;
    if (__float_as_uint(v.z) > tb) local += (double)v.z;
    if (__float_as_uint(v.w) > tb) local += (double)v.w;
  }
  if (blockIdx.x == 0) {
    for (int p = (n4 << 2) + tid; p < P; p += 256) {
      const float v = row[p];
      if (__float_as_uint(v) > tb) local += (double)v;
    }
    if (tid == 0 && rem1 > 0)
      local += (double)rem1 * (double)__uint_as_float((pref24 << 8) | 0x80u);
  }
  __shared__ double red[256];
  red[tid] = local;
  __syncthreads();
  for (int s = 128; s > 0; s >>= 1) {
    if (tid < s) red[tid] += red[tid + s];
    __syncthreads();
  }
  if (tid == 0) {
    if (red[0] != 0.0) atomicAdd(&phard[b], red[0]);
    __threadfence();
    const unsigned done = atomicAdd(counter, 1u);
    if (done == gridDim.x * gridDim.y - 1) {
      double tp = 0.0, cs = 0.0, ls = 0.0, hs = 0.0;
      for (int i = 0; i < B; ++i) {
        tp += (double)n_pos[i];
        cs += pconf[i];
        ls += ploc[i];
        hs += atomicAdd(&phard[i], 0.0);
      }
      out[0] = (float)((hs + cs) / tp);
      out[1] = (float)(ls / (tp * 6.0));
    }
  }
}

extern "C" void kernel_launch(void* const* d_in, const int* in_sizes, int n_in,
                              void* d_out, int out_size, void* d_ws, size_t ws_size,
                              hipStream_t stream) {
  const float* locs = (const float*)d_in[0];
  const float* scores = (const float*)d_in[1];
  const float* boxes = (const float*)d_in[2];
  const int* labels = (const int*)d_in[3];
  const float* priors = (const float*)d_in[4];

  const long long sz_locs = (long long)in_sizes[0];
  const long long sz_scores = (long long)in_sizes[1];
  const long long sz_priors = (long long)in_sizes[4];
  const int P = (int)(sz_priors / 6);
  const int B = (int)(sz_locs / sz_priors);
  const int n_obj = in_sizes[3] / B;
  const int C = (int)(sz_scores * 6 / sz_locs);

  char* ws = (char*)d_ws;
  size_t off = 0;
  double* pconf = (double*)(ws + off); off += (size_t)B * 8;
  double* ploc = (double*)(ws + off); off += (size_t)B * 8;
  double* phard = (double*)(ws + off); off += (size_t)B * 8;
  int* n_pos = (int*)(ws + off); off += ((size_t)B * 4 + 15) & ~(size_t)15;
  unsigned* counter = (unsigned*)(ws + off); off += 16;
  unsigned long long* prior_fo = (unsigned long long*)(ws + off);
  off += (size_t)B * 64 * 8;
  unsigned* hist0 = (unsigned*)(ws + off); off += (size_t)B * 4096 * 4;
  unsigned* hist1 = (unsigned*)(ws + off); off += (size_t)B * 4096 * 4;
  const size_t zero_bytes = off;
  float* conf_neg = (float*)(ws + off); off += ((size_t)B * P * 4 + 15) & ~(size_t)15;
  unsigned char* best_u8 = (unsigned char*)(ws + off);
  off += ((size_t)B * P + 15) & ~(size_t)15;
  (void)ws_size;

  hipMemsetAsync(d_ws, 0, zero_bytes, stream);

  const int nblk = (P + TILE - 1) / TILE;
  const dim3 mgrid(nblk, B);
  const bool full = (P % TILE) == 0;
  if (n_obj <= 16) {
    if (full) mbl_match2<16, true><<<mgrid, 256, 0, stream>>>(boxes, priors, prior_fo, best_u8, P, n_obj);
    else      mbl_match2<16, false><<<mgrid, 256, 0, stream>>>(boxes, priors, prior_fo, best_u8, P, n_obj);
  } else if (n_obj <= 32) {
    if (full) mbl_match2<32, true><<<mgrid, 256, 0, stream>>>(boxes, priors, prior_fo, best_u8, P, n_obj);
    else      mbl_match2<32, false><<<mgrid, 256, 0, stream>>>(boxes, priors, prior_fo, best_u8, P, n_obj);
  } else {
    if (full) mbl_match2<64, true><<<mgrid, 256, 0, stream>>>(boxes, priors, prior_fo, best_u8, P, n_obj);
    else      mbl_match2<64, false><<<mgrid, 256, 0, stream>>>(boxes, priors, prior_fo, best_u8, P, n_obj);
  }

  const dim3 lgrid(LB, B);
  if (C == 2)
    mbl_loss<2><<<lgrid, 256, 0, stream>>>(locs, scores, boxes, labels, priors,
                                           prior_fo, best_u8, conf_neg, hist0, n_pos,
                                           pconf, ploc, P, n_obj, C);
  else
    mbl_loss<0><<<lgrid, 256, 0, stream>>>(locs, scores, boxes, labels, priors,
                                           prior_fo, best_u8, conf_neg, hist0, n_pos,
                                           pconf, ploc, P, n_obj, C);

  mbl_hist1<<<lgrid, 256, 0, stream>>>(conf_neg, n_pos, hist0, hist1, P);
  mbl_sum<<<lgrid, 256, 0, stream>>>(conf_neg, n_pos, hist0, hist1, pconf, ploc,
                                     phard, counter, P, B, (float*)d_out);
}